// Round 5
// baseline (198.352 us; speedup 1.0000x reference)
//
#include <hip/hip_runtime.h>
#include <hip/hip_bf16.h>
#include <math.h>

#define NB 16
#define NS 512
#define ND 2048

typedef __attribute__((ext_vector_type(4))) float  f32x4v;
typedef __attribute__((ext_vector_type(8))) short  short8v;
typedef __attribute__((ext_vector_type(4))) float  accv;

__device__ __forceinline__ unsigned short f2bf(float f) {
  union { float f; unsigned u; } v; v.f = f;
  unsigned r = v.u + 0x7FFFu + ((v.u >> 16) & 1u);   // RNE
  return (unsigned short)(r >> 16);
}

// swizzled 16B-unit index within an 8KB tile image (128 rows x 4 k-quads)
__device__ __forceinline__ int swz(int r, int kq) { return r * 4 + (kq ^ ((r >> 1) & 3)); }

#define GLL16(gp, lp) __builtin_amdgcn_global_load_lds(                        \
    (const __attribute__((address_space(1))) void*)(gp),                       \
    (__attribute__((address_space(3))) void*)(lp), 16, 0, 0)

// ---------------- K1: W fp32 -> bf16 swizzled tile images ----------------
// image layout: [e][mp][ks] -> 512 x 16B units; unit swz(r,kq) holds W[e][mp*128+r][ks*32+kq*8 .. +7]
__global__ __launch_bounds__(256) void k_wcvt(const float* __restrict__ W,
                                              unsigned short* __restrict__ Aimg) {
  int ks = blockIdx.x, mp = blockIdx.y, e = blockIdx.z;
  size_t img = ((size_t)(e * 4 + mp) * 16 + ks) * 4096;   // ushort units
  int tid = threadIdx.x;
#pragma unroll
  for (int u = 0; u < 2; ++u) {
    int p = u * 256 + tid;
    int r = p >> 2, cc = p & 3;
    int kq = cc ^ ((r >> 1) & 3);
    const float* src = W + ((size_t)e * NS + mp * 128 + r) * NS + ks * 32 + kq * 8;
    f32x4v v0 = *reinterpret_cast<const f32x4v*>(src);
    f32x4v v1 = *reinterpret_cast<const f32x4v*>(src + 4);
    short8v o;
#pragma unroll
    for (int j = 0; j < 4; ++j) { o[j] = (short)f2bf(v0[j]); o[4 + j] = (short)f2bf(v1[j]); }
    *reinterpret_cast<short8v*>(Aimg + img + (size_t)p * 8) = o;
  }
}

// ---------------- K2: fused LayerNorm (stats + normalize + transpose) ----------------
// One block = 32 rows (t) x full D, 512 threads. Row data held in registers:
// thread (tA=tid>>4, dqA=(tid&15)*4) owns x[t0+tA][dqA + 64k], k=0..31.
// Stats: width-16 shuffle reduce (rows are lane-group-local). Output yT[b][d][t] bf16.
__global__ __launch_bounds__(512) void k_ln(const float* __restrict__ x,
                                            const float* __restrict__ gamma,
                                            const float* __restrict__ beta,
                                            unsigned short* __restrict__ yT) {
  int t0 = blockIdx.x * 32;
  int bb = blockIdx.y;
  int tid = threadIdx.x;
  int tA  = tid >> 4;            // local row 0..31
  int dqA = (tid & 15) * 4;      // col base (mod 64)
  const float* xr = x + ((size_t)bb * NS + t0 + tA) * ND + dqA;
  f32x4v xv[32];
#pragma unroll
  for (int k = 0; k < 32; ++k) xv[k] = *reinterpret_cast<const f32x4v*>(xr + k * 64);
  float s = 0.f, ss = 0.f;
#pragma unroll
  for (int k = 0; k < 32; ++k)
#pragma unroll
    for (int j = 0; j < 4; ++j) { float f = xv[k][j]; s += f; ss += f * f; }
#pragma unroll
  for (int off = 1; off < 16; off <<= 1) {
    s  += __shfl_xor(s, off);
    ss += __shfl_xor(ss, off);
  }
  float mean = s * (1.0f / ND);
  float rstd = rsqrtf(ss * (1.0f / ND) - mean * mean + 1e-5f);

  // transpose tile: 32t x 64d per step, double-buffered, XOR-swizzled u32 words
  __shared__ unsigned tw[2][1024];
  int dlR = tid >> 3;            // 0..63  (local d)
  int tcR = (tid & 7) * 4;       // 0..28  (t chunk)
  unsigned short* yTb = yT + (size_t)bb * ND * NS + t0;
  int wb = dqA >> 1;             // word base 0..30 (even)
#pragma unroll
  for (int k = 0; k < 32; ++k) {
    int d0 = k * 64;
    f32x4v g = *reinterpret_cast<const f32x4v*>(gamma + d0 + dqA);
    f32x4v b = *reinterpret_cast<const f32x4v*>(beta  + d0 + dqA);
    unsigned short h[4];
#pragma unroll
    for (int j = 0; j < 4; ++j) h[j] = f2bf((xv[k][j] - mean) * rstd * g[j] + b[j]);
    unsigned* twb = tw[k & 1];
    twb[tA * 32 + ((wb    ) ^ tA)] = (unsigned)h[0] | ((unsigned)h[1] << 16);
    twb[tA * 32 + ((wb + 1) ^ tA)] = (unsigned)h[2] | ((unsigned)h[3] << 16);
    __syncthreads();
    unsigned short o[4];
#pragma unroll
    for (int i = 0; i < 4; ++i) {
      int t = tcR + i;
      unsigned w = twb[t * 32 + ((dlR >> 1) ^ t)];
      o[i] = (dlR & 1) ? (unsigned short)(w >> 16) : (unsigned short)(w & 0xffffu);
    }
    *reinterpret_cast<ushort4*>(yTb + (size_t)(d0 + dlR) * NS + tcR) =
        make_ushort4(o[0], o[1], o[2], o[3]);
    // no barrier here: next iteration writes the other buffer; the barrier of
    // iteration k+1 orders those reads before buffer k's reuse at k+2.
  }
}

// ---------------- K3: out = gelu(W_e @ y + bias_e) + x ----------------
// BM=128 BN=128 BK=32, 4 waves (2x2), 4x4 mfma_f32_16x16x32_bf16 per wave.
// 2-phase pipeline: double-buffered LDS, stage(next) issued before compute(cur),
// ONE barrier per K-step. B staged straight from yT with pre-swizzled per-lane
// global source addresses (same permutation the A images bake in).
__global__ __launch_bounds__(256) void k_gemm(const unsigned short* __restrict__ Aimg,
                                              const unsigned short* __restrict__ yT,
                                              const float* __restrict__ bias,
                                              const float* __restrict__ x,
                                              float* __restrict__ out) {
  int np = blockIdx.x, mp = blockIdx.y, bb = blockIdx.z;
  int e = bb < 3 ? bb : 3;
  const char* Abase = (const char*)(Aimg + ((size_t)(e * 4 + mp) * 16) * 4096);
  int n0 = np * 128;
  __shared__ unsigned short Al[2][4096];
  __shared__ unsigned short Bl[2][4096];
  int tid = threadIdx.x;
  int lane = tid & 63, wid = tid >> 6;
  int wr = wid >> 1, wc = wid & 1;
  int lr = lane & 15, kq = lane >> 4;

  int aoff[4], boff[4];
#pragma unroll
  for (int mi = 0; mi < 4; ++mi) { int rr = wr * 64 + mi * 16 + lr; aoff[mi] = swz(rr, kq) * 8; }
#pragma unroll
  for (int ni = 0; ni < 4; ++ni) { int rr = wc * 64 + ni * 16 + lr; boff[ni] = swz(rr, kq) * 8; }

  // per-lane pre-swizzled B source: LDS slot (r, cc) must receive k-quad kq = cc ^ ((r>>1)&3)
  int rs = tid >> 2, cs = tid & 3;
  int kqs = cs ^ ((rs >> 1) & 3);
  const char* Bsrc = (const char*)(yT + (size_t)bb * ND * NS + (size_t)(n0 + rs) * NS) + kqs * 16;

  accv acc[4][4] = {};

#define STAGE(bufi, ks)                                                                  \
  do {                                                                                   \
    GLL16(Abase + (ks) * 8192 +        tid * 16, (char*)Al[bufi] +        wid * 1024);   \
    GLL16(Abase + (ks) * 8192 + 4096 + tid * 16, (char*)Al[bufi] + 4096 + wid * 1024);   \
    GLL16(Bsrc  + (ks) * 64,                     (char*)Bl[bufi] +        wid * 1024);   \
    GLL16(Bsrc  + (ks) * 64 + 65536,             (char*)Bl[bufi] + 4096 + wid * 1024);   \
  } while (0)

  STAGE(0, 0);
  for (int ks = 0; ks < 16; ++ks) {
    __syncthreads();                       // tile ks staged (implicit vmcnt drain)
    if (ks < 15) STAGE((ks + 1) & 1, ks + 1);   // overlap next-tile loads with MFMA
    const unsigned short* Ab = Al[ks & 1];
    const unsigned short* Bb = Bl[ks & 1];
    short8v a[4], b[4];
#pragma unroll
    for (int mi = 0; mi < 4; ++mi) a[mi] = *reinterpret_cast<const short8v*>(&Ab[aoff[mi]]);
#pragma unroll
    for (int ni = 0; ni < 4; ++ni) b[ni] = *reinterpret_cast<const short8v*>(&Bb[boff[ni]]);
#pragma unroll
    for (int mi = 0; mi < 4; ++mi)
#pragma unroll
      for (int ni = 0; ni < 4; ++ni)
        acc[mi][ni] = __builtin_amdgcn_mfma_f32_16x16x32_bf16(a[mi], b[ni], acc[mi][ni], 0, 0, 0);
  }
#undef STAGE

  // epilogue: gelu(acc + bias_e[s]) + x   (sigmoid-form gelu)
  const float* bp = bias + (size_t)e * NS;
  int m0 = mp * 128;
#pragma unroll
  for (int mi = 0; mi < 4; ++mi) {
#pragma unroll
    for (int ni = 0; ni < 4; ++ni) {
#pragma unroll
      for (int r = 0; r < 4; ++r) {
        int s = m0 + wr * 64 + mi * 16 + ((lane >> 4) * 4) + r;
        int d = n0 + wc * 64 + ni * 16 + (lane & 15);
        float v = acc[mi][ni][r] + bp[s];
        float u = 1.5957691216f * (v + 0.044715f * v * v * v);
        float g = v / (1.0f + __expf(-u));
        size_t idx = ((size_t)bb * NS + s) * ND + d;
        out[idx] = g + x[idx];
      }
    }
  }
}

extern "C" void kernel_launch(void* const* d_in, const int* in_sizes, int n_in,
                              void* d_out, int out_size, void* d_ws, size_t ws_size,
                              hipStream_t stream) {
  const float* x     = (const float*)d_in[0];
  const float* gamma = (const float*)d_in[1];
  const float* beta  = (const float*)d_in[2];
  // d_in[3] = Wc, d_in[4] = bc : router is dead code in the reference (unused output)
  const float* W     = (const float*)d_in[5];
  const float* bias  = (const float*)d_in[6];
  float* out = (float*)d_out;

  // ws layout: Aimg 2MiB | yT 32MiB
  unsigned short* Aimg = (unsigned short*)d_ws;
  unsigned short* yT   = (unsigned short*)((char*)d_ws + (2ull << 20));

  k_wcvt<<<dim3(16, 4, 4), 256, 0, stream>>>(W, Aimg);
  k_ln<<<dim3(NS / 32, NB), 512, 0, stream>>>(x, gamma, beta, yT);
  k_gemm<<<dim3(ND / 128, NS / 128, NB), 256, 0, stream>>>(Aimg, yT, bias, x, out);
}

// Round 6
// 175.554 us; speedup vs baseline: 1.1299x; 1.1299x over previous
//
#include <hip/hip_runtime.h>
#include <hip/hip_bf16.h>
#include <math.h>

#define NB 16
#define NS 512
#define ND 2048

typedef __attribute__((ext_vector_type(4))) float  f32x4v;
typedef __attribute__((ext_vector_type(8))) short  short8v;
typedef __attribute__((ext_vector_type(4))) float  accv;

__device__ __forceinline__ unsigned short f2bf(float f) {
  union { float f; unsigned u; } v; v.f = f;
  unsigned r = v.u + 0x7FFFu + ((v.u >> 16) & 1u);   // RNE
  return (unsigned short)(r >> 16);
}

// swizzled 16B-unit index within an 8KB tile image (128 rows x 4 k-quads)
__device__ __forceinline__ int swz(int r, int kq) { return r * 4 + (kq ^ ((r >> 1) & 3)); }

#define GLL16(gp, lp) __builtin_amdgcn_global_load_lds(                        \
    (const __attribute__((address_space(1))) void*)(gp),                       \
    (__attribute__((address_space(3))) void*)(lp), 16, 0, 0)

// ---------------- K1: per-row mean / rstd (wave per row) ----------------
__global__ __launch_bounds__(256) void k_stats(const float* __restrict__ x,
                                               float* __restrict__ mv) {
  int row  = blockIdx.x * 4 + (threadIdx.x >> 6);
  int lane = threadIdx.x & 63;
  const float* xr = x + (size_t)row * ND;
  float s = 0.f, ss = 0.f;
#pragma unroll
  for (int q = 0; q < 8; ++q) {
    f32x4v v = *reinterpret_cast<const f32x4v*>(xr + q * 256 + lane * 4);
#pragma unroll
    for (int j = 0; j < 4; ++j) { s += v[j]; ss += v[j] * v[j]; }
  }
#pragma unroll
  for (int off = 1; off < 64; off <<= 1) {
    s  += __shfl_xor(s, off);
    ss += __shfl_xor(ss, off);
  }
  if (lane == 0) {
    float mean = s * (1.0f / ND);
    float var  = ss * (1.0f / ND) - mean * mean;
    mv[2 * row]     = mean;
    mv[2 * row + 1] = rsqrtf(var + 1e-5f);
  }
}

// ---------------- K2: W fp32 -> bf16 swizzled tile images ----------------
// image layout: [e][mp][ks] -> 512 x 16B units; unit swz(r,kq) holds W[e][mp*128+r][ks*32+kq*8 .. +7]
__global__ __launch_bounds__(256) void k_wcvt(const float* __restrict__ W,
                                              unsigned short* __restrict__ Aimg) {
  int ks = blockIdx.x, mp = blockIdx.y, e = blockIdx.z;
  size_t img = ((size_t)(e * 4 + mp) * 16 + ks) * 4096;   // ushort units
  int tid = threadIdx.x;
#pragma unroll
  for (int u = 0; u < 2; ++u) {
    int p = u * 256 + tid;
    int r = p >> 2, cc = p & 3;
    int kq = cc ^ ((r >> 1) & 3);
    const float* src = W + ((size_t)e * NS + mp * 128 + r) * NS + ks * 32 + kq * 8;
    f32x4v v0 = *reinterpret_cast<const f32x4v*>(src);
    f32x4v v1 = *reinterpret_cast<const f32x4v*>(src + 4);
    short8v o;
#pragma unroll
    for (int j = 0; j < 4; ++j) { o[j] = (short)f2bf(v0[j]); o[4 + j] = (short)f2bf(v1[j]); }
    *reinterpret_cast<short8v*>(Aimg + img + (size_t)p * 8) = o;
  }
}

// ---------------- K3: normalize + transpose -> B tile images ----------------
// tile 32t x 64d, 256 threads. Phase1: thread (tA=tid>>3, dq=(tid&7)*8) normalizes
// 8 d's of one row into LDS words (XOR ^tA swizzle, 2 lanes/bank = free).
// Phase2: thread (dl=tid>>2, th=(tid&3)*8) gathers 8 t's at one d = one 16B image
// unit; a wave's 64 units land in 1KB contiguous (swz-permuted inside). Content
// identical to round-2's k_normT image spec (verified passing).
__global__ __launch_bounds__(256) void k_lnT(const float* __restrict__ x,
                                             const float* __restrict__ mv,
                                             const float* __restrict__ gamma,
                                             const float* __restrict__ beta,
                                             unsigned short* __restrict__ Bimg) {
  int d0 = blockIdx.x * 64, t0 = blockIdx.y * 32, bb = blockIdx.z;
  __shared__ unsigned tw[1024];            // 32 rows x 32 words
  int tid = threadIdx.x;
  {
    int tA = tid >> 3;                     // 0..31
    int dq = (tid & 7) * 8;                // 0..56
    int row = bb * NS + t0 + tA;
    float mean = mv[2 * row], rstd = mv[2 * row + 1];
    const float* xr = x + (size_t)row * ND + d0 + dq;
    f32x4v v0 = *reinterpret_cast<const f32x4v*>(xr);
    f32x4v v1 = *reinterpret_cast<const f32x4v*>(xr + 4);
    f32x4v g0 = *reinterpret_cast<const f32x4v*>(gamma + d0 + dq);
    f32x4v g1 = *reinterpret_cast<const f32x4v*>(gamma + d0 + dq + 4);
    f32x4v b0 = *reinterpret_cast<const f32x4v*>(beta + d0 + dq);
    f32x4v b1 = *reinterpret_cast<const f32x4v*>(beta + d0 + dq + 4);
    unsigned short h[8];
#pragma unroll
    for (int j = 0; j < 4; ++j) {
      h[j]     = f2bf((v0[j] - mean) * rstd * g0[j] + b0[j]);
      h[4 + j] = f2bf((v1[j] - mean) * rstd * g1[j] + b1[j]);
    }
    int wb = dq >> 1;                      // 0..28, step 4
#pragma unroll
    for (int q = 0; q < 4; ++q)
      tw[tA * 32 + ((wb + q) ^ tA)] = (unsigned)h[2 * q] | ((unsigned)h[2 * q + 1] << 16);
  }
  __syncthreads();
  {
    int dl = tid >> 2;                     // 0..63 (local d)
    int th = (tid & 3) * 8;                // 0,8,16,24 (t chunk = k-quad)
    short8v o;
#pragma unroll
    for (int i = 0; i < 8; ++i) {
      int t = th + i;
      unsigned w = tw[t * 32 + ((dl >> 1) ^ t)];
      o[i] = (short)((dl & 1) ? (unsigned short)(w >> 16) : (unsigned short)(w & 0xffffu));
    }
    int d  = d0 + dl;
    int r  = d & 127, np = d >> 7;
    int ks = t0 >> 5;
    int kq = th >> 3;
    size_t img = ((size_t)(bb * 16 + np) * 16 + ks) * 4096;   // ushort units
    *reinterpret_cast<short8v*>(Bimg + img + (size_t)swz(r, kq) * 8) = o;
  }
}

// ---------------- K4: out = gelu(W_e @ y + bias_e) + x ----------------
// BM=128 BN=128 BK=32, 4 waves (2x2), 4x4 mfma_f32_16x16x32_bf16 per wave.
// Depth-2 pipeline: triple-buffered LDS, counted s_waitcnt vmcnt(4) — tile ks
// was issued two iterations earlier, so ~2 compute phases hide HBM latency.
// Both A and B staged from contiguous images (round-2 proven source pattern).
__global__ __launch_bounds__(256) void k_gemm(const unsigned short* __restrict__ Aimg,
                                              const unsigned short* __restrict__ Bimg,
                                              const float* __restrict__ bias,
                                              const float* __restrict__ x,
                                              float* __restrict__ out) {
  int np = blockIdx.x, mp = blockIdx.y, bb = blockIdx.z;
  int e = bb < 3 ? bb : 3;
  const char* Abase = (const char*)(Aimg + ((size_t)(e  * 4 + mp) * 16) * 4096);
  const char* Bbase = (const char*)(Bimg + ((size_t)(bb * 16 + np) * 16) * 4096);
  __shared__ unsigned short Al[3 * 4096];
  __shared__ unsigned short Bl[3 * 4096];
  int tid = threadIdx.x;
  int lane = tid & 63, wid = tid >> 6;
  int wr = wid >> 1, wc = wid & 1;
  int lr = lane & 15, kq = lane >> 4;

  int aoff[4], boff[4];
#pragma unroll
  for (int mi = 0; mi < 4; ++mi) { int rr = wr * 64 + mi * 16 + lr; aoff[mi] = swz(rr, kq) * 8; }
#pragma unroll
  for (int ni = 0; ni < 4; ++ni) { int rr = wc * 64 + ni * 16 + lr; boff[ni] = swz(rr, kq) * 8; }

  accv acc[4][4] = {};

#define STAGE(p, ks)                                                                     \
  do {                                                                                   \
    GLL16(Abase + (ks) * 8192 +        tid * 16, (char*)Al + (p) * 8192 +        wid * 1024); \
    GLL16(Abase + (ks) * 8192 + 4096 + tid * 16, (char*)Al + (p) * 8192 + 4096 + wid * 1024); \
    GLL16(Bbase + (ks) * 8192 +        tid * 16, (char*)Bl + (p) * 8192 +        wid * 1024); \
    GLL16(Bbase + (ks) * 8192 + 4096 + tid * 16, (char*)Bl + (p) * 8192 + 4096 + wid * 1024); \
  } while (0)

  STAGE(0, 0);
  STAGE(1, 1);
#pragma unroll
  for (int ks = 0; ks < 16; ++ks) {
    if (ks == 15) asm volatile("s_waitcnt vmcnt(0)" ::: "memory");
    else          asm volatile("s_waitcnt vmcnt(4)" ::: "memory");
    __builtin_amdgcn_s_barrier();
    __builtin_amdgcn_sched_barrier(0);
    if (ks + 2 < 16) STAGE((ks + 2) % 3, ks + 2);
    const unsigned short* Ab = Al + (ks % 3) * 4096;
    const unsigned short* Bb = Bl + (ks % 3) * 4096;
    short8v a[4], b[4];
#pragma unroll
    for (int mi = 0; mi < 4; ++mi) a[mi] = *reinterpret_cast<const short8v*>(&Ab[aoff[mi]]);
#pragma unroll
    for (int ni = 0; ni < 4; ++ni) b[ni] = *reinterpret_cast<const short8v*>(&Bb[boff[ni]]);
#pragma unroll
    for (int mi = 0; mi < 4; ++mi)
#pragma unroll
      for (int ni = 0; ni < 4; ++ni)
        acc[mi][ni] = __builtin_amdgcn_mfma_f32_16x16x32_bf16(a[mi], b[ni], acc[mi][ni], 0, 0, 0);
    asm volatile("" ::: "memory");
  }
#undef STAGE

  // epilogue: gelu(acc + bias_e[s]) + x   (sigmoid-form gelu)
  const float* bp = bias + (size_t)e * NS;
  int m0 = mp * 128, n0 = np * 128;
#pragma unroll
  for (int mi = 0; mi < 4; ++mi) {
#pragma unroll
    for (int ni = 0; ni < 4; ++ni) {
#pragma unroll
      for (int r = 0; r < 4; ++r) {
        int s = m0 + wr * 64 + mi * 16 + ((lane >> 4) * 4) + r;
        int d = n0 + wc * 64 + ni * 16 + lr;
        float v = acc[mi][ni][r] + bp[s];
        float u = 1.5957691216f * (v + 0.044715f * v * v * v);
        float g = v / (1.0f + __expf(-u));
        size_t idx = ((size_t)bb * NS + s) * ND + d;
        out[idx] = g + x[idx];
      }
    }
  }
}

extern "C" void kernel_launch(void* const* d_in, const int* in_sizes, int n_in,
                              void* d_out, int out_size, void* d_ws, size_t ws_size,
                              hipStream_t stream) {
  const float* x     = (const float*)d_in[0];
  const float* gamma = (const float*)d_in[1];
  const float* beta  = (const float*)d_in[2];
  // d_in[3] = Wc, d_in[4] = bc : router is dead code in the reference (unused output)
  const float* W     = (const float*)d_in[5];
  const float* bias  = (const float*)d_in[6];
  float* out = (float*)d_out;

  // ws layout: Aimg 2MiB | Bimg 32MiB | mv 64KiB
  unsigned short* Aimg = (unsigned short*)d_ws;
  unsigned short* Bimg = (unsigned short*)((char*)d_ws + (2ull << 20));
  float*          mv   = (float*)((char*)d_ws + (34ull << 20));

  k_stats<<<NB * NS / 4, 256, 0, stream>>>(x, mv);
  k_wcvt<<<dim3(16, 4, 4), 256, 0, stream>>>(W, Aimg);
  k_lnT<<<dim3(ND / 64, NS / 32, NB), 256, 0, stream>>>(x, mv, gamma, beta, Bimg);
  k_gemm<<<dim3(ND / 128, NS / 128, NB), 256, 0, stream>>>(Aimg, Bimg, bias, x, out);
}